// Round 12
// baseline (1361.987 us; speedup 1.0000x reference)
//
#include <hip/hip_runtime.h>
#include <cmath>

#define NB 4
#define TT 2048
#define DD 256
#define NH 4
#define BT (NB*TT)   // 8192 rows

static constexpr float DT_ = 0.25f;

typedef _Float16 f16x8 __attribute__((ext_vector_type(8)));
typedef _Float16 f16x4 __attribute__((ext_vector_type(4)));
typedef float    f32x4 __attribute__((ext_vector_type(4)));
typedef float    f32x16 __attribute__((ext_vector_type(16)));

static constexpr size_t HSZ = (size_t)NB * NH * TT * 64;   // per split Q/K array: 2M halves
static constexpr size_t FSZ = (size_t)BT * 256;            // one partial-F buffer (floats)

// async global->LDS, 16B per lane; LDS dest is wave-uniform base + lane*16
__device__ __forceinline__ void gload16(const void* g, void* l) {
    __builtin_amdgcn_global_load_lds(
        (const __attribute__((address_space(1))) void*)g,
        (__attribute__((address_space(3))) void*)l,
        16, 0, 0);
}

// ---------------- split W into fp16 hi/lo (runs once per launch) ----------------
__global__ __launch_bounds__(256)
void split_weights(const float* __restrict__ Wqk, const float* __restrict__ Wout,
                   _Float16* __restrict__ WqkH, _Float16* __restrict__ WqkL,
                   _Float16* __restrict__ WoutH, _Float16* __restrict__ WoutL)
{
    const int idx = blockIdx.x * 256 + threadIdx.x;   // float4 group index
    const float4 v = (idx < 32768) ? ((const float4*)Wqk)[idx]
                                   : ((const float4*)Wout)[idx - 32768];
    f16x4 h, l;
    h[0]=(_Float16)v.x; l[0]=(_Float16)(v.x-(float)h[0]);
    h[1]=(_Float16)v.y; l[1]=(_Float16)(v.y-(float)h[1]);
    h[2]=(_Float16)v.z; l[2]=(_Float16)(v.z-(float)h[2]);
    h[3]=(_Float16)v.w; l[3]=(_Float16)(v.w-(float)h[3]);
    if (idx < 32768) { ((f16x4*)WqkH)[idx] = h; ((f16x4*)WqkL)[idx] = l; }
    else { ((f16x4*)WoutH)[idx-32768] = h; ((f16x4*)WoutL)[idx-32768] = l; }
}

// ---------------- Wcomb = Wqk @ Wout  [512,256], split fp16; qkob = (omega+bout)@Wqk^T ----
__global__ __launch_bounds__(256)
void comb_weights(const float* __restrict__ Wqk, const float* __restrict__ Wout,
                  const float* __restrict__ omega, const float* __restrict__ bout,
                  _Float16* __restrict__ WcombH, _Float16* __restrict__ WcombL,
                  float* __restrict__ qkob)
{
    __shared__ float qrow[256];
    __shared__ float pr[256];
    const int n = blockIdx.x;      // 512 blocks
    const int k = threadIdx.x;
    qrow[k] = Wqk[n * 256 + k];
    __syncthreads();
    float s = 0.f;
    for (int m = 0; m < 256; ++m) s = fmaf(qrow[m], Wout[m * 256 + k], s);
    const _Float16 h = (_Float16)s;
    WcombH[n * 256 + k] = h;
    WcombL[n * 256 + k] = (_Float16)(s - (float)h);
    pr[k] = (omega[k] + bout[k]) * qrow[k];
    __syncthreads();
    if (k == 0) {
        float t = 0.f;
        for (int i = 0; i < 256; ++i) t += pr[i];
        qkob[n] = t;
    }
}

// ---------------- row-wise l2 norm over D=256; optional fp16 split emit ----------------
__global__ __launch_bounds__(256)
void l2norm_rows(const float* __restrict__ src, float* __restrict__ dst,
                 _Float16* __restrict__ dstH, _Float16* __restrict__ dstL) {
    const int wave = threadIdx.x >> 6;
    const int lane = threadIdx.x & 63;
    const size_t row = (size_t)blockIdx.x * 4 + wave;
    float4 v = ((const float4*)(src + row * DD))[lane];
    float ss = v.x*v.x + v.y*v.y + v.z*v.z + v.w*v.w;
    #pragma unroll
    for (int off = 32; off; off >>= 1) ss += __shfl_xor(ss, off, 64);
    const float inv = 1.0f / fmaxf(sqrtf(ss), 1e-12f);
    v.x *= inv; v.y *= inv; v.z *= inv; v.w *= inv;
    ((float4*)(dst + row * DD))[lane] = v;
    if (dstH != nullptr) {
        f16x4 h, l;
        h[0]=(_Float16)v.x; l[0]=(_Float16)(v.x-(float)h[0]);
        h[1]=(_Float16)v.y; l[1]=(_Float16)(v.y-(float)h[1]);
        h[2]=(_Float16)v.z; l[2]=(_Float16)(v.z-(float)h[2]);
        h[3]=(_Float16)v.w; l[3]=(_Float16)(v.w-(float)h[3]);
        ((f16x4*)(dstH + row * DD))[lane] = h;
        ((f16x4*)(dstL + row * DD))[lane] = l;
    }
}

// ---------------- split-fp16 MFMA GEMM, 128m x 64n tile, 3 modes ----------------
// mode 0: A = xs (split fp16) staged via global_load_lds. qk = x@Wqk^T -> qkx, Q/K/Ktr.
// mode 1: A = sum of 3 Fp partials (fused reduce); y==0 maintains Facc. epilogue qk_s.
// mode 2: A = Facc + sum of 3 Fp partials. epilogue x update.
// K emitted in tile-chunked layout KC[bh][jt][c][r] (attn reads coalesced from L2);
// K^T emitted permuted+chunked KD[bh][jt][cu][d] -> attn PV frag = 1 coalesced b128.
__global__ __launch_bounds__(256, 2)
void gemm_mfma(const _Float16* __restrict__ AH, const _Float16* __restrict__ AL,
               const _Float16* __restrict__ BH, const _Float16* __restrict__ BL,
               const float* __restrict__ Fp, float* __restrict__ FaccP,
               float* __restrict__ qkx, const float* __restrict__ qkob,
               const float* __restrict__ omega, const float* __restrict__ bout,
               const float* __restrict__ xin, float* __restrict__ xout,
               _Float16* __restrict__ Qhi, _Float16* __restrict__ Qlo,
               _Float16* __restrict__ KChi, _Float16* __restrict__ KClo,
               _Float16* __restrict__ KD,
               int mode, float cc, int faccm)
{
    __shared__ _Float16 Ah[128 * 64];
    __shared__ _Float16 Al[128 * 64];
    __shared__ _Float16 Bh[64 * 64];
    __shared__ _Float16 Bl[64 * 64];
    const int m0 = blockIdx.x * 128, n0 = blockIdx.y * 64;
    const int t  = threadIdx.x;
    const int w  = t >> 6;
    const int l  = t & 63;
    const int lr = l & 15;
    const int lq = l >> 4;
    const int m7 = lr & 7;
    const int rr = l >> 3;                    // row-in-group 0..7
    const int lc  = l & 7;                    // logical chunk 0..7
    const int cg  = (lc ^ rr) * 8;            // inverse-swizzled source chunk (halves)
    const int swd = (lc ^ rr) * 8;            // swizzled LDS dest chunk (halves)
    const bool yzero = (blockIdx.y == 0);

    f32x4 acc[2][4];
    #pragma unroll
    for (int s = 0; s < 2; ++s)
        #pragma unroll
        for (int nt = 0; nt < 4; ++nt) acc[s][nt] = (f32x4){0.f,0.f,0.f,0.f};

#define GSTAGE_A(K0) do { \
        _Pragma("unroll") \
        for (int a = 0; a < 4; ++a) { \
            const int rg = 8*w + 32*a; \
            gload16(AH + (size_t)(m0 + rg + rr) * 256 + (K0) + cg, &Ah[rg * 64]); \
            gload16(AL + (size_t)(m0 + rg + rr) * 256 + (K0) + cg, &Al[rg * 64]); \
        } \
    } while (0)

#define GSTAGE_B(K0) do { \
        _Pragma("unroll") \
        for (int a = 0; a < 2; ++a) { \
            const int rg = 8*w + 32*a; \
            gload16(BH + (size_t)(n0 + rg + rr) * 256 + (K0) + cg, &Bh[rg * 64]); \
            gload16(BL + (size_t)(n0 + rg + rr) * 256 + (K0) + cg, &Bl[rg * 64]); \
        } \
    } while (0)

// fused-reduce A staging (modes 1/2): sum 3 partials (+Facc for faccm3), split, ds_write
#define FSTAGE(K0) do { \
        _Pragma("unroll") \
        for (int a = 0; a < 4; ++a) { \
            const int row = 8*w + 32*a + rr; \
            const size_t go = (size_t)(m0 + row) * 256 + (K0) + lc * 8; \
            float sv[8]; \
            { const float4 a0 = *(const float4*)(Fp + go); \
              const float4 a1 = *(const float4*)(Fp + go + 4); \
              sv[0]=a0.x; sv[1]=a0.y; sv[2]=a0.z; sv[3]=a0.w; \
              sv[4]=a1.x; sv[5]=a1.y; sv[6]=a1.z; sv[7]=a1.w; } \
            _Pragma("unroll") \
            for (int p = 1; p < 3; ++p) { \
                const float4 a0 = *(const float4*)(Fp + (size_t)p*FSZ + go); \
                const float4 a1 = *(const float4*)(Fp + (size_t)p*FSZ + go + 4); \
                sv[0]+=a0.x; sv[1]+=a0.y; sv[2]+=a0.z; sv[3]+=a0.w; \
                sv[4]+=a1.x; sv[5]+=a1.y; sv[6]+=a1.z; sv[7]+=a1.w; } \
            if (faccm == 3) { \
                const float4 f0 = *(const float4*)(FaccP + go); \
                const float4 f1 = *(const float4*)(FaccP + go + 4); \
                sv[0]+=f0.x; sv[1]+=f0.y; sv[2]+=f0.z; sv[3]+=f0.w; \
                sv[4]+=f1.x; sv[5]+=f1.y; sv[6]+=f1.z; sv[7]+=f1.w; \
            } else if (yzero) { \
                if (faccm == 1) { \
                    *(float4*)(FaccP + go)     = make_float4(sv[0], sv[1], sv[2], sv[3]); \
                    *(float4*)(FaccP + go + 4) = make_float4(sv[4], sv[5], sv[6], sv[7]); \
                } else { \
                    float4 f0 = *(const float4*)(FaccP + go); \
                    float4 f1 = *(const float4*)(FaccP + go + 4); \
                    f0.x += 2.f*sv[0]; f0.y += 2.f*sv[1]; f0.z += 2.f*sv[2]; f0.w += 2.f*sv[3]; \
                    f1.x += 2.f*sv[4]; f1.y += 2.f*sv[5]; f1.z += 2.f*sv[6]; f1.w += 2.f*sv[7]; \
                    *(float4*)(FaccP + go)     = f0; \
                    *(float4*)(FaccP + go + 4) = f1; \
                } \
            } \
            f16x8 hv, lv; \
            _Pragma("unroll") \
            for (int e = 0; e < 8; ++e) { \
                hv[e] = (_Float16)sv[e]; \
                lv[e] = (_Float16)(sv[e] - (float)hv[e]); } \
            *(f16x8*)&Ah[row * 64 + swd] = hv; \
            *(f16x8*)&Al[row * 64 + swd] = lv; \
        } \
    } while (0)

    if (mode == 0) GSTAGE_A(0); else FSTAGE(0);
    GSTAGE_B(0);
    asm volatile("s_waitcnt vmcnt(0) lgkmcnt(0)" ::: "memory");
    __builtin_amdgcn_s_barrier();
    asm volatile("" ::: "memory");

    for (int kc = 0; kc < 4; ++kc) {
        // hoist ALL of this kc's fragments into registers
        f16x8 ah[2][2], al[2][2], bh[2][4], bl[2][4];
        #pragma unroll
        for (int c = 0; c < 2; ++c) {
            const int xo = (((4*c + lq) ^ m7) << 4);
            #pragma unroll
            for (int s = 0; s < 2; ++s) {
                ah[c][s] = *(const f16x8*)((const char*)Ah + (32*w + 16*s + lr) * 128 + xo);
                al[c][s] = *(const f16x8*)((const char*)Al + (32*w + 16*s + lr) * 128 + xo);
            }
            #pragma unroll
            for (int nt = 0; nt < 4; ++nt) {
                bh[c][nt] = *(const f16x8*)((const char*)Bh + (16*nt + lr) * 128 + xo);
                bl[c][nt] = *(const f16x8*)((const char*)Bl + (16*nt + lr) * 128 + xo);
            }
        }
        asm volatile("s_waitcnt lgkmcnt(0)" ::: "memory");
        __builtin_amdgcn_s_barrier();          // all waves done reading LDS
        asm volatile("" ::: "memory");
        if (kc < 3) {                          // stage kc+1 while computing from regs
            GSTAGE_B((kc + 1) * 64);
            if (mode == 0) GSTAGE_A((kc + 1) * 64); else FSTAGE((kc + 1) * 64);
        }
        #pragma unroll
        for (int c = 0; c < 2; ++c)
            #pragma unroll
            for (int s = 0; s < 2; ++s)
                #pragma unroll
                for (int nt = 0; nt < 4; ++nt) {
                    acc[s][nt] = __builtin_amdgcn_mfma_f32_16x16x32_f16(ah[c][s], bh[c][nt], acc[s][nt], 0, 0, 0);
                    acc[s][nt] = __builtin_amdgcn_mfma_f32_16x16x32_f16(ah[c][s], bl[c][nt], acc[s][nt], 0, 0, 0);
                    acc[s][nt] = __builtin_amdgcn_mfma_f32_16x16x32_f16(al[c][s], bh[c][nt], acc[s][nt], 0, 0, 0);
                }
        if (kc < 3) asm volatile("s_waitcnt vmcnt(0) lgkmcnt(0)" ::: "memory");
        __builtin_amdgcn_s_barrier();
        asm volatile("" ::: "memory");
    }
#undef GSTAGE_A
#undef GSTAGE_B
#undef FSTAGE

    if (mode == 2) {
        #pragma unroll
        for (int s = 0; s < 2; ++s) {
            const int row0 = m0 + 32*w + 16*s + 4*lq;
            #pragma unroll
            for (int nt = 0; nt < 4; ++nt) {
                const int col = n0 + 16*nt + lr;
                const float ob = omega[col] + bout[col];
                #pragma unroll
                for (int r = 0; r < 4; ++r) {
                    const size_t off = (size_t)(row0 + r) * 256 + col;
                    xout[off] = xin[off] + (DT_ / 6.0f) * acc[s][nt][r] + DT_ * ob;
                }
            }
        }
    } else {
        float val[2][4][4];
        #pragma unroll
        for (int s = 0; s < 2; ++s) {
            const int row0 = m0 + 32*w + 16*s + 4*lq;
            #pragma unroll
            for (int nt = 0; nt < 4; ++nt) {
                const int col = n0 + 16*nt + lr;
                #pragma unroll
                for (int r = 0; r < 4; ++r) {
                    const size_t qo = (size_t)(row0 + r) * 512 + col;
                    if (mode == 0) {
                        val[s][nt][r] = acc[s][nt][r];
                        qkx[qo] = acc[s][nt][r];
                    } else {
                        val[s][nt][r] = qkx[qo] + cc * (acc[s][nt][r] + qkob[col]);
                    }
                }
            }
        }
        float ss[2][4];
        #pragma unroll
        for (int s = 0; s < 2; ++s)
            #pragma unroll
            for (int r = 0; r < 4; ++r) {
                float v = 0.f;
                #pragma unroll
                for (int nt = 0; nt < 4; ++nt) v += val[s][nt][r] * val[s][nt][r];
                ss[s][r] = v;
            }
        #pragma unroll
        for (int off = 1; off < 16; off <<= 1)
            #pragma unroll
            for (int s = 0; s < 2; ++s)
                #pragma unroll
                for (int r = 0; r < 4; ++r)
                    ss[s][r] += __shfl_xor(ss[s][r], off, 64);
        const int  b    = m0 >> 11;
        const int  h    = (n0 >> 6) & 3;
        const bool is_k = (n0 >= 256);
        const size_t bhi = (size_t)b * NH + h;
        _Float16* dhi = is_k ? nullptr : (Qhi + bhi * (size_t)TT * 64);
        _Float16* dlo = is_k ? nullptr : (Qlo + bhi * (size_t)TT * 64);
        const int mloc = m0 & (TT - 1);
        _Float16* Pt = Ah;   // 16KB transpose tile [64 d][128 m], XOR-swizzled
        #pragma unroll
        for (int s = 0; s < 2; ++s) {
            const int r0 = 32*w + 16*s + 4*lq;
            float inv[4];
            #pragma unroll
            for (int r = 0; r < 4; ++r) inv[r] = 1.0f / fmaxf(sqrtf(ss[s][r]), 1e-12f);
            #pragma unroll
            for (int nt = 0; nt < 4; ++nt) {
                const int d = 16*nt + lr;
                f16x4 hv, lv;
                #pragma unroll
                for (int r = 0; r < 4; ++r) {
                    const float v2 = val[s][nt][r] * inv[r];
                    hv[r] = (_Float16)v2;
                    lv[r] = (_Float16)(v2 - (float)hv[r]);
                    if (!is_k) {
                        dhi[(size_t)(mloc + r0 + r) * 64 + d] = hv[r];
                        dlo[(size_t)(mloc + r0 + r) * 64 + d] = lv[r];
                    } else {
                        // KC[bh][jt][c][r]: chunked K layout for coalesced attn reads
                        const int j = mloc + r0 + r;
                        const size_t ka = ((size_t)(bhi * 32 + (j >> 6)) * 8 + (d >> 3)) * 512
                                          + (j & 63) * 8 + (d & 7);
                        KChi[ka] = hv[r];
                        KClo[ka] = lv[r];
                    }
                }
                if (is_k) {
                    *(f16x4*)((char*)Pt + d * 256 + ((r0 * 2) ^ ((d & 7) << 4))) = hv;
                }
            }
        }
        if (is_k) {
            __syncthreads();
            #pragma unroll
            for (int p = 0; p < 4; ++p) {
                const int d   = (t >> 4) + 16 * p;
                const int g   = t & 15;            // 2 windows x 8 units
                const int win = g >> 3, gw = g & 7;
                const int Ga  = 16*win + 4*(gw >> 1) + (gw & 1);  // orig 4-half group
                const int Gb  = Ga + 2;
                f16x4 va = *(const f16x4*)((const char*)Pt + d * 256 + ((8*Ga) ^ ((d & 7) << 4)));
                f16x4 vb = *(const f16x4*)((const char*)Pt + d * 256 + ((8*Gb) ^ ((d & 7) << 4)));
                f16x8 v;
                #pragma unroll
                for (int e = 0; e < 4; ++e) { v[e] = va[e]; v[4 + e] = vb[e]; }
                // KD[bh][jt][cu][d]: permuted K^T, coalesced for attn PV
                const size_t da = ((size_t)(bhi * 32 + (mloc >> 6) + win) * 8 + gw) * 512 + d * 8;
                *(f16x8*)(KD + da) = v;
            }
        }
    }
}

// ---------------- F_partial = sin(Q K^T) K over a j third ----------------
// ZERO-LDS, ZERO-BARRIER attn: K fragments read directly from L2 (per-XCD resident
// via bh-first grid) using the chunked KC/KD layouts -> every wave read is 2x512B
// or 1KB contiguous. 32x32x16 zero-shuffle compute (HW-validated R8/R11).
__global__ __launch_bounds__(256, 3)
void kuramoto_attn(const _Float16* __restrict__ Qhi, const _Float16* __restrict__ Qlo,
                   const _Float16* __restrict__ KChi, const _Float16* __restrict__ KClo,
                   const _Float16* __restrict__ KD,
                   float* __restrict__ Fp)
{
    const int bh = blockIdx.x;             // fastest dim -> XCD = bh%8
    const int b  = bh >> 2, h = bh & 3;
    const size_t qbase  = (size_t)bh * TT * 64;
    const size_t kcbase = (size_t)bh * 32 * 4096;   // (bh*32 + jt) * 4096 halves
    const int t0 = blockIdx.y * 11;
    const int tn = (blockIdx.y == 2) ? 10 : 11;
    float* Fout = Fp + (size_t)blockIdx.y * FSZ;
    const int t = threadIdx.x;
    const int w = t >> 6;
    const int l = t & 63;
    const int il = l & 31;                 // i-row within wave / d-col within dblk
    const int h5 = l >> 5;                 // k-ordinal half
    const int i0 = blockIdx.z * 128 + w * 32;

    // Q fragments: lane holds Q[i0+il][16*kc + 8*h5 .. +7]  (B-operand layout)
    f16x8 qh[4], ql[4];
    #pragma unroll
    for (int kc = 0; kc < 4; ++kc) {
        const size_t qoff = qbase + (size_t)(i0 + il) * 64 + 16*kc + 8*h5;
        qh[kc] = *(const f16x8*)(Qhi + qoff);
        ql[kc] = *(const f16x8*)(Qlo + qoff);
    }

    f32x16 Fac[2];
    #pragma unroll
    for (int db = 0; db < 2; ++db)
        #pragma unroll
        for (int r = 0; r < 16; ++r) Fac[db][r] = 0.f;

    for (int tt = 0; tt < tn; ++tt) {
        const size_t tb = kcbase + (size_t)(t0 + tt) * 4096;
        const _Float16* pH = KChi + tb;
        const _Float16* pL = KClo + tb;
        const _Float16* pD = KD + tb;

        // ---- QK^T: per jb, split chains sA (hh) / sB (lh+hl); sin -> packed P frags ----
        f16x8 ph[2][2];
        #pragma unroll
        for (int jb = 0; jb < 2; ++jb) {
            f32x16 sA, sB;
            #pragma unroll
            for (int r = 0; r < 16; ++r) { sA[r] = 0.f; sB[r] = 0.f; }
            const int ro = (32*jb + il) * 8;
            __builtin_amdgcn_s_setprio(1);
            #pragma unroll
            for (int kc = 0; kc < 4; ++kc) {
                const int co = (2*kc + h5) * 512;
                f16x8 khA = *(const f16x8*)(pH + co + ro);
                f16x8 klA = *(const f16x8*)(pL + co + ro);
                sA = __builtin_amdgcn_mfma_f32_32x32x16_f16(khA, qh[kc], sA, 0, 0, 0);
                sB = __builtin_amdgcn_mfma_f32_32x32x16_f16(klA, qh[kc], sB, 0, 0, 0);
                sB = __builtin_amdgcn_mfma_f32_32x32x16_f16(khA, ql[kc], sB, 0, 0, 0);
            }
            __builtin_amdgcn_s_setprio(0);
            f16x8 v0, v1;
            #pragma unroll
            for (int e = 0; e < 8; ++e) {
                v0[e] = (_Float16)__sinf(sA[e] + sB[e]);
                v1[e] = (_Float16)__sinf(sA[8 + e] + sB[8 + e]);
            }
            ph[jb][0] = v0;
            ph[jb][1] = v1;
        }

        // ---- PV: F += P*K; B-frag = single coalesced b128 from KD ----
        #pragma unroll
        for (int db = 0; db < 2; ++db) {
            const int dro = (il + 32*db) * 8;
            __builtin_amdgcn_s_setprio(1);
            #pragma unroll
            for (int cp = 0; cp < 4; ++cp) {
                f16x8 kf = *(const f16x8*)(pD + (2*cp + h5) * 512 + dro);
                Fac[db] = __builtin_amdgcn_mfma_f32_32x32x16_f16(ph[cp >> 1][cp & 1], kf, Fac[db], 0, 0, 0);
            }
            __builtin_amdgcn_s_setprio(0);
        }
    }

    // D layout (32x32): col = il (+32*db) = d, row i = (r&3) + 8*(r>>2) + 4*h5
    #pragma unroll
    for (int db = 0; db < 2; ++db)
        #pragma unroll
        for (int r = 0; r < 16; ++r) {
            const int irow = (r & 3) + 8 * (r >> 2) + 4 * h5;
            Fout[((size_t)b * TT + i0 + irow) * 256 + h * 64 + il + 32 * db] = Fac[db][r];
        }
}

extern "C" void kernel_launch(void* const* d_in, const int* in_sizes, int n_in,
                              void* d_out, int out_size, void* d_ws, size_t ws_size,
                              hipStream_t stream) {
    const float* z     = (const float*)d_in[0];
    const float* omega = (const float*)d_in[1];
    const float* Wqk   = (const float*)d_in[2];
    const float* Wout  = (const float*)d_in[3];
    const float* bout  = (const float*)d_in[4];

    float* x    = (float*)d_ws;                  // [BT,256] fp32 state
    float* Facc = x + FSZ;                       // [BT,256] weighted force accumulator
    float* Fp   = Facc + FSZ;                    // [3][BT,256] fp32 partial forces
    float* qkx  = Fp + 3 * FSZ;                  // [BT,512] raw qk of step-start x
    float* qkob = qkx + (size_t)BT * 512;        // [512]
    _Float16* xsH  = (_Float16*)(qkob + 512);
    _Float16* xsL  = xsH  + FSZ;
    _Float16* Qhi  = xsL  + FSZ;
    _Float16* Qlo  = Qhi  + HSZ;
    _Float16* KChi = Qlo  + HSZ;
    _Float16* KClo = KChi + HSZ;
    _Float16* KD   = KClo + HSZ;
    _Float16* WqkH = KD   + HSZ;
    _Float16* WqkL = WqkH + (size_t)512 * 256;
    _Float16* WoutH= WqkL + (size_t)512 * 256;
    _Float16* WoutL= WoutH + (size_t)256 * 256;
    _Float16* WcombH = WoutL + (size_t)256 * 256;   // [512,256]
    _Float16* WcombL = WcombH + (size_t)512 * 256;

    split_weights<<<192, 256, 0, stream>>>(Wqk, Wout, WqkH, WqkL, WoutH, WoutL);
    comb_weights<<<512, 256, 0, stream>>>(Wqk, Wout, omega, bout, WcombH, WcombL, qkob);

    for (int step = 0; step < 4; ++step) {
        l2norm_rows<<<BT / 4, 256, 0, stream>>>(step == 0 ? z : x, x, xsH, xsL);
        // stage 0: qk = x@Wqk^T (stores qkx + emits Q/K)
        gemm_mfma<<<dim3(BT / 128, 8), 256, 0, stream>>>(
            xsH, xsL, WqkH, WqkL, nullptr, nullptr, qkx, nullptr,
            nullptr, nullptr, nullptr, nullptr,
            Qhi, Qlo, KChi, KClo, KD, 0, 0.f, 0);
        kuramoto_attn<<<dim3(NB * NH, 3, TT / 128), 256, 0, stream>>>(
            Qhi, Qlo, KChi, KClo, KD, Fp);
        // stages 1..3: fused reduce in A-staging; qk_s = qkx + c_s*(Fs@Wcomb + qkob)
        for (int s = 1; s <= 3; ++s) {
            const float cs = (s == 3) ? 0.25f : 0.125f;
            gemm_mfma<<<dim3(BT / 128, 8), 256, 0, stream>>>(
                nullptr, nullptr, WcombH, WcombL, Fp, Facc, qkx, qkob,
                nullptr, nullptr, nullptr, nullptr,
                Qhi, Qlo, KChi, KClo, KD, 1, cs, (s == 1) ? 1 : 2);
            kuramoto_attn<<<dim3(NB * NH, 3, TT / 128), 256, 0, stream>>>(
                Qhi, Qlo, KChi, KClo, KD, Fp);
        }
        // final: x += DT/6 * (Facc + F4)@Wout^T + DT*(omega+bout)
        gemm_mfma<<<dim3(BT / 128, 4), 256, 0, stream>>>(
            nullptr, nullptr, WoutH, WoutL, Fp, Facc, nullptr, nullptr,
            omega, bout, x, x,
            nullptr, nullptr, nullptr, nullptr, nullptr, 2, 0.f, 3);
    }
    l2norm_rows<<<BT / 4, 256, 0, stream>>>(x, (float*)d_out, nullptr, nullptr);
}

// Round 13
// 1152.832 us; speedup vs baseline: 1.1814x; 1.1814x over previous
//
#include <hip/hip_runtime.h>
#include <cmath>

#define NB 4
#define TT 2048
#define DD 256
#define NH 4
#define BT (NB*TT)   // 8192 rows

static constexpr float DT_ = 0.25f;

typedef _Float16 f16x8 __attribute__((ext_vector_type(8)));
typedef _Float16 f16x4 __attribute__((ext_vector_type(4)));
typedef float    f32x4 __attribute__((ext_vector_type(4)));

static constexpr size_t HSZ = (size_t)NB * NH * TT * 64;   // per split Q/K array: 2M halves
static constexpr size_t FSZ = (size_t)BT * 256;            // one partial-F buffer (floats)

// async global->LDS, 16B per lane; LDS dest is wave-uniform base + lane*16
__device__ __forceinline__ void gload16(const void* g, void* l) {
    __builtin_amdgcn_global_load_lds(
        (const __attribute__((address_space(1))) void*)g,
        (__attribute__((address_space(3))) void*)l,
        16, 0, 0);
}

// ---------------- split W into fp16 hi/lo (runs once per launch) ----------------
__global__ __launch_bounds__(256)
void split_weights(const float* __restrict__ Wqk, const float* __restrict__ Wout,
                   _Float16* __restrict__ WqkH, _Float16* __restrict__ WqkL,
                   _Float16* __restrict__ WoutH, _Float16* __restrict__ WoutL)
{
    const int idx = blockIdx.x * 256 + threadIdx.x;   // float4 group index
    const float4 v = (idx < 32768) ? ((const float4*)Wqk)[idx]
                                   : ((const float4*)Wout)[idx - 32768];
    f16x4 h, l;
    h[0]=(_Float16)v.x; l[0]=(_Float16)(v.x-(float)h[0]);
    h[1]=(_Float16)v.y; l[1]=(_Float16)(v.y-(float)h[1]);
    h[2]=(_Float16)v.z; l[2]=(_Float16)(v.z-(float)h[2]);
    h[3]=(_Float16)v.w; l[3]=(_Float16)(v.w-(float)h[3]);
    if (idx < 32768) { ((f16x4*)WqkH)[idx] = h; ((f16x4*)WqkL)[idx] = l; }
    else { ((f16x4*)WoutH)[idx-32768] = h; ((f16x4*)WoutL)[idx-32768] = l; }
}

// ---------------- Wcomb = Wqk @ Wout  [512,256], split fp16; qkob = (omega+bout)@Wqk^T ----
__global__ __launch_bounds__(256)
void comb_weights(const float* __restrict__ Wqk, const float* __restrict__ Wout,
                  const float* __restrict__ omega, const float* __restrict__ bout,
                  _Float16* __restrict__ WcombH, _Float16* __restrict__ WcombL,
                  float* __restrict__ qkob)
{
    __shared__ float qrow[256];
    __shared__ float pr[256];
    const int n = blockIdx.x;      // 512 blocks
    const int k = threadIdx.x;
    qrow[k] = Wqk[n * 256 + k];
    __syncthreads();
    float s = 0.f;
    for (int m = 0; m < 256; ++m) s = fmaf(qrow[m], Wout[m * 256 + k], s);
    const _Float16 h = (_Float16)s;
    WcombH[n * 256 + k] = h;
    WcombL[n * 256 + k] = (_Float16)(s - (float)h);
    pr[k] = (omega[k] + bout[k]) * qrow[k];
    __syncthreads();
    if (k == 0) {
        float t = 0.f;
        for (int i = 0; i < 256; ++i) t += pr[i];
        qkob[n] = t;
    }
}

// ---------------- row-wise l2 norm over D=256; optional fp16 split emit ----------------
__global__ __launch_bounds__(256)
void l2norm_rows(const float* __restrict__ src, float* __restrict__ dst,
                 _Float16* __restrict__ dstH, _Float16* __restrict__ dstL) {
    const int wave = threadIdx.x >> 6;
    const int lane = threadIdx.x & 63;
    const size_t row = (size_t)blockIdx.x * 4 + wave;
    float4 v = ((const float4*)(src + row * DD))[lane];
    float ss = v.x*v.x + v.y*v.y + v.z*v.z + v.w*v.w;
    #pragma unroll
    for (int off = 32; off; off >>= 1) ss += __shfl_xor(ss, off, 64);
    const float inv = 1.0f / fmaxf(sqrtf(ss), 1e-12f);
    v.x *= inv; v.y *= inv; v.z *= inv; v.w *= inv;
    ((float4*)(dst + row * DD))[lane] = v;
    if (dstH != nullptr) {
        f16x4 h, l;
        h[0]=(_Float16)v.x; l[0]=(_Float16)(v.x-(float)h[0]);
        h[1]=(_Float16)v.y; l[1]=(_Float16)(v.y-(float)h[1]);
        h[2]=(_Float16)v.z; l[2]=(_Float16)(v.z-(float)h[2]);
        h[3]=(_Float16)v.w; l[3]=(_Float16)(v.w-(float)h[3]);
        ((f16x4*)(dstH + row * DD))[lane] = h;
        ((f16x4*)(dstL + row * DD))[lane] = l;
    }
}

// ---------------- reduce 3 F partials (+Facc bookkeeping) -> fp16 split A ----------------
__global__ __launch_bounds__(256)
void reduce_F(const float* __restrict__ Fp, float* __restrict__ Facc,
              _Float16* __restrict__ SH, _Float16* __restrict__ SL, int faccm)
{
    const size_t idx = (size_t)blockIdx.x * 256 + threadIdx.x;   // float4 index
    const float4 a = ((const float4*)Fp)[idx];
    const float4 b = ((const float4*)(Fp + FSZ))[idx];
    const float4 c = ((const float4*)(Fp + 2*FSZ))[idx];
    float4 s = make_float4(a.x+b.x+c.x, a.y+b.y+c.y, a.z+b.z+c.z, a.w+b.w+c.w);
    if (faccm == 1) {
        ((float4*)Facc)[idx] = s;
    } else if (faccm == 2) {
        float4 f = ((const float4*)Facc)[idx];
        f.x += 2.f*s.x; f.y += 2.f*s.y; f.z += 2.f*s.z; f.w += 2.f*s.w;
        ((float4*)Facc)[idx] = f;
    } else {
        const float4 f = ((const float4*)Facc)[idx];
        s.x += f.x; s.y += f.y; s.z += f.z; s.w += f.w;
    }
    f16x4 h, l;
    h[0]=(_Float16)s.x; l[0]=(_Float16)(s.x-(float)h[0]);
    h[1]=(_Float16)s.y; l[1]=(_Float16)(s.y-(float)h[1]);
    h[2]=(_Float16)s.z; l[2]=(_Float16)(s.z-(float)h[2]);
    h[3]=(_Float16)s.w; l[3]=(_Float16)(s.w-(float)h[3]);
    ((f16x4*)SH)[idx] = h;
    ((f16x4*)SL)[idx] = l;
}

// ---------------- split-fp16 MFMA GEMM, 128m x 64n tile, 3 modes ----------------
// 2-phase K-loop: fragments for kc hoisted to regs, then kc+1 staged via
// global_load_lds into the SAME LDS while MFMAs run from regs (no dbuf needed).
// KtrH emitted via LDS transpose (reuse Ah) -> fully coalesced 16B stores.
__global__ __launch_bounds__(256, 2)
void gemm_mfma(const _Float16* __restrict__ AH, const _Float16* __restrict__ AL,
               const _Float16* __restrict__ BH, const _Float16* __restrict__ BL,
               float* __restrict__ qkx, const float* __restrict__ qkob,
               const float* __restrict__ omega, const float* __restrict__ bout,
               const float* __restrict__ xin, float* __restrict__ xout,
               _Float16* __restrict__ Qhi, _Float16* __restrict__ Qlo,
               _Float16* __restrict__ Khi, _Float16* __restrict__ Klo,
               _Float16* __restrict__ KtrH,
               int mode, float cc)
{
    __shared__ _Float16 Ah[128 * 64];
    __shared__ _Float16 Al[128 * 64];
    __shared__ _Float16 Bh[64 * 64];
    __shared__ _Float16 Bl[64 * 64];
    const int m0 = blockIdx.x * 128, n0 = blockIdx.y * 64;
    const int t  = threadIdx.x;
    const int w  = t >> 6;
    const int l  = t & 63;
    const int lr = l & 15;
    const int lq = l >> 4;
    const int m7 = lr & 7;
    const int rr = l >> 3;                    // row-in-group 0..7
    const int cg = ((l & 7) ^ rr) * 8;        // inverse-swizzled source chunk (halves)

    f32x4 acc[2][4];
    #pragma unroll
    for (int s = 0; s < 2; ++s)
        #pragma unroll
        for (int nt = 0; nt < 4; ++nt) acc[s][nt] = (f32x4){0.f,0.f,0.f,0.f};

#define GSTAGE(K0) do { \
        _Pragma("unroll") \
        for (int a = 0; a < 4; ++a) { \
            const int rg = 8*w + 32*a; \
            gload16(AH + (size_t)(m0 + rg + rr) * 256 + (K0) + cg, &Ah[rg * 64]); \
            gload16(AL + (size_t)(m0 + rg + rr) * 256 + (K0) + cg, &Al[rg * 64]); \
            if (a < 2) { \
                gload16(BH + (size_t)(n0 + rg + rr) * 256 + (K0) + cg, &Bh[rg * 64]); \
                gload16(BL + (size_t)(n0 + rg + rr) * 256 + (K0) + cg, &Bl[rg * 64]); \
            } \
        } \
    } while (0)

    GSTAGE(0);
    asm volatile("s_waitcnt vmcnt(0)" ::: "memory");
    __builtin_amdgcn_s_barrier();

    for (int kc = 0; kc < 4; ++kc) {
        // hoist ALL of this kc's fragments into registers
        f16x8 ah[2][2], al[2][2], bh[2][4], bl[2][4];
        #pragma unroll
        for (int c = 0; c < 2; ++c) {
            const int xo = (((4*c + lq) ^ m7) << 4);
            #pragma unroll
            for (int s = 0; s < 2; ++s) {
                ah[c][s] = *(const f16x8*)((const char*)Ah + (32*w + 16*s + lr) * 128 + xo);
                al[c][s] = *(const f16x8*)((const char*)Al + (32*w + 16*s + lr) * 128 + xo);
            }
            #pragma unroll
            for (int nt = 0; nt < 4; ++nt) {
                bh[c][nt] = *(const f16x8*)((const char*)Bh + (16*nt + lr) * 128 + xo);
                bl[c][nt] = *(const f16x8*)((const char*)Bl + (16*nt + lr) * 128 + xo);
            }
        }
        asm volatile("s_waitcnt lgkmcnt(0)" ::: "memory");
        __builtin_amdgcn_s_barrier();          // all waves done reading LDS
        if (kc < 3) GSTAGE((kc + 1) * 64);     // overwrite LDS while computing from regs
        #pragma unroll
        for (int c = 0; c < 2; ++c)
            #pragma unroll
            for (int s = 0; s < 2; ++s)
                #pragma unroll
                for (int nt = 0; nt < 4; ++nt) {
                    acc[s][nt] = __builtin_amdgcn_mfma_f32_16x16x32_f16(ah[c][s], bh[c][nt], acc[s][nt], 0, 0, 0);
                    acc[s][nt] = __builtin_amdgcn_mfma_f32_16x16x32_f16(ah[c][s], bl[c][nt], acc[s][nt], 0, 0, 0);
                    acc[s][nt] = __builtin_amdgcn_mfma_f32_16x16x32_f16(al[c][s], bh[c][nt], acc[s][nt], 0, 0, 0);
                }
        if (kc < 3) asm volatile("s_waitcnt vmcnt(0)" ::: "memory");
        __builtin_amdgcn_s_barrier();
        asm volatile("" ::: "memory");
    }
#undef GSTAGE

    if (mode == 2) {
        #pragma unroll
        for (int s = 0; s < 2; ++s) {
            const int row0 = m0 + 32*w + 16*s + 4*lq;
            #pragma unroll
            for (int nt = 0; nt < 4; ++nt) {
                const int col = n0 + 16*nt + lr;
                const float ob = omega[col] + bout[col];
                #pragma unroll
                for (int r = 0; r < 4; ++r) {
                    const size_t off = (size_t)(row0 + r) * 256 + col;
                    xout[off] = xin[off] + (DT_ / 6.0f) * acc[s][nt][r] + DT_ * ob;
                }
            }
        }
    } else {
        float val[2][4][4];
        #pragma unroll
        for (int s = 0; s < 2; ++s) {
            const int row0 = m0 + 32*w + 16*s + 4*lq;
            #pragma unroll
            for (int nt = 0; nt < 4; ++nt) {
                const int col = n0 + 16*nt + lr;
                #pragma unroll
                for (int r = 0; r < 4; ++r) {
                    const size_t qo = (size_t)(row0 + r) * 512 + col;
                    if (mode == 0) {
                        val[s][nt][r] = acc[s][nt][r];
                        qkx[qo] = acc[s][nt][r];
                    } else {
                        val[s][nt][r] = qkx[qo] + cc * (acc[s][nt][r] + qkob[col]);
                    }
                }
            }
        }
        float ss[2][4];
        #pragma unroll
        for (int s = 0; s < 2; ++s)
            #pragma unroll
            for (int r = 0; r < 4; ++r) {
                float v = 0.f;
                #pragma unroll
                for (int nt = 0; nt < 4; ++nt) v += val[s][nt][r] * val[s][nt][r];
                ss[s][r] = v;
            }
        #pragma unroll
        for (int off = 1; off < 16; off <<= 1)
            #pragma unroll
            for (int s = 0; s < 2; ++s)
                #pragma unroll
                for (int r = 0; r < 4; ++r)
                    ss[s][r] += __shfl_xor(ss[s][r], off, 64);
        const int  b    = m0 >> 11;
        const int  h    = (n0 >> 6) & 3;
        const bool is_k = (n0 >= 256);
        const size_t bhi = (size_t)b * NH + h;
        _Float16* dhi = (is_k ? Khi : Qhi) + bhi * (size_t)TT * 64;
        _Float16* dlo = (is_k ? Klo : Qlo) + bhi * (size_t)TT * 64;
        const int mloc = m0 & (TT - 1);
        _Float16* Pt = Ah;   // 16KB transpose tile [64 d][128 m], XOR-swizzled
        #pragma unroll
        for (int s = 0; s < 2; ++s) {
            const int r0 = 32*w + 16*s + 4*lq;
            float inv[4];
            #pragma unroll
            for (int r = 0; r < 4; ++r) inv[r] = 1.0f / fmaxf(sqrtf(ss[s][r]), 1e-12f);
            #pragma unroll
            for (int nt = 0; nt < 4; ++nt) {
                const int d = 16*nt + lr;
                f16x4 hv, lv;
                #pragma unroll
                for (int r = 0; r < 4; ++r) {
                    const float v2 = val[s][nt][r] * inv[r];
                    hv[r] = (_Float16)v2;
                    lv[r] = (_Float16)(v2 - (float)hv[r]);
                    dhi[(size_t)(mloc + r0 + r) * 64 + d] = hv[r];
                    dlo[(size_t)(mloc + r0 + r) * 64 + d] = lv[r];
                }
                if (is_k) {
                    *(f16x4*)((char*)Pt + d * 256 + ((r0 * 2) ^ ((d & 7) << 4))) = hv;
                }
            }
        }
        if (is_k) {
            __syncthreads();
            const size_t kb = bhi * (size_t)64 * TT + mloc;
            #pragma unroll
            for (int p = 0; p < 4; ++p) {
                const int d   = (t >> 4) + 16 * p;
                const int lm0 = (t & 15) * 8;
                f16x8 v = *(const f16x8*)((const char*)Pt + d * 256 + ((lm0 * 2) ^ ((d & 7) << 4)));
                *(f16x8*)(KtrH + kb + (size_t)d * TT + lm0) = v;
            }
        }
    }
}

// ---------------- F_partial = sin(Q K^T) K over a j third ----------------
// LDS tiles XOR-swizzled, reg-prefetch staging across raw barriers,
// bh-first grid (XCD = bh%8). 40KB LDS -> 3 blocks/CU.
__global__ __launch_bounds__(256, 3)
void kuramoto_attn(const _Float16* __restrict__ Qhi, const _Float16* __restrict__ Qlo,
                   const _Float16* __restrict__ Khi, const _Float16* __restrict__ Klo,
                   const _Float16* __restrict__ KtrH,
                   float* __restrict__ Fp)
{
    __shared__ _Float16 KjH[64 * 64];
    __shared__ _Float16 KjL[64 * 64];
    __shared__ _Float16 KdH[64 * 64];
    __shared__ _Float16 Pw[4][2][16 * 64];
    const int bh = blockIdx.x;             // fastest dim -> XCD = bh%8
    const int b  = bh >> 2, h = bh & 3;
    const size_t base  = (size_t)bh * TT * 64;
    const size_t tbase = (size_t)bh * 64 * TT;
    const int t0 = blockIdx.y * 11;
    const int tn = (blockIdx.y == 2) ? 10 : 11;
    float* Fout = Fp + (size_t)blockIdx.y * FSZ;
    const int t = threadIdx.x;
    const int w = t >> 6;
    const int l = t & 63;
    const int lr = l & 15;
    const int lq = l >> 4;
    const int i0 = blockIdx.z * 128 + w * 32;
    const int m7 = lr & 7;
    const int x0 = ((lq ^ m7) << 4);          // byte offset, read chunk lq
    const int x1 = (((lq + 4) ^ m7) << 4);    // byte offset, read chunk lq+4
    const int rr = l >> 3;                    // row-in-group 0..7
    const int lc8 = (l & 7) * 8;              // linear source chunk (halves)
    const int sw = ((l & 7) ^ rr) * 8;        // swizzled LDS dest chunk (halves)
    const int rg = 8 * w + rr;                // this lane's staged row (and rg+32)

    f16x8 qh[2][2], ql[2][2];
    #pragma unroll
    for (int s = 0; s < 2; ++s) {
        const size_t qoff = base + (size_t)(i0 + 16*s + lr) * 64 + lq * 8;
        qh[s][0] = *(const f16x8*)(Qhi + qoff);
        qh[s][1] = *(const f16x8*)(Qhi + qoff + 32);
        ql[s][0] = *(const f16x8*)(Qlo + qoff);
        ql[s][1] = *(const f16x8*)(Qlo + qoff + 32);
    }

    f32x4 Facc[2][4];
    #pragma unroll
    for (int s = 0; s < 2; ++s)
        #pragma unroll
        for (int nt = 0; nt < 4; ++nt) Facc[s][nt] = (f32x4){0.f, 0.f, 0.f, 0.f};

    uint4 gA0, gA1, gB0, gB1, gC0, gC1;   // staged tile: KjH rows rg/rg+32, KjL, KdH
#define GLOAD(TTi) do { \
        const int j0_ = (t0 + (TTi)) * 64; \
        gA0 = *(const uint4*)(Khi  + base  + (size_t)(j0_ + rg)      * 64 + lc8); \
        gA1 = *(const uint4*)(Khi  + base  + (size_t)(j0_ + rg + 32) * 64 + lc8); \
        gB0 = *(const uint4*)(Klo  + base  + (size_t)(j0_ + rg)      * 64 + lc8); \
        gB1 = *(const uint4*)(Klo  + base  + (size_t)(j0_ + rg + 32) * 64 + lc8); \
        gC0 = *(const uint4*)(KtrH + tbase + (size_t)rg        * TT + j0_ + lc8); \
        gC1 = *(const uint4*)(KtrH + tbase + (size_t)(rg + 32) * TT + j0_ + lc8); \
    } while (0)

    GLOAD(0);

    for (int tt = 0; tt < tn; ++tt) {
        *(uint4*)&KjH[rg * 64 + sw]        = gA0;
        *(uint4*)&KjH[(rg + 32) * 64 + sw] = gA1;
        *(uint4*)&KjL[rg * 64 + sw]        = gB0;
        *(uint4*)&KjL[(rg + 32) * 64 + sw] = gB1;
        *(uint4*)&KdH[rg * 64 + sw]        = gC0;
        *(uint4*)&KdH[(rg + 32) * 64 + sw] = gC1;
        if (tt + 1 < tn) GLOAD(tt + 1);   // prefetch next tile into regs
        asm volatile("s_waitcnt lgkmcnt(0)" ::: "memory");
        __builtin_amdgcn_s_barrier();
        asm volatile("" ::: "memory");

        #pragma unroll
        for (int nt = 0; nt < 4; ++nt) {
            const int rb = (16*nt + lr) * 128;
            f16x8 kh0 = *(const f16x8*)((const char*)KjH + rb + x0);
            f16x8 kh1 = *(const f16x8*)((const char*)KjH + rb + x1);
            f16x8 kl0 = *(const f16x8*)((const char*)KjL + rb + x0);
            f16x8 kl1 = *(const f16x8*)((const char*)KjL + rb + x1);
            #pragma unroll
            for (int s = 0; s < 2; ++s) {
                f32x4 a = (f32x4){0.f, 0.f, 0.f, 0.f};
                __builtin_amdgcn_s_setprio(1);
                a = __builtin_amdgcn_mfma_f32_16x16x32_f16(kh0, qh[s][0], a, 0, 0, 0);
                a = __builtin_amdgcn_mfma_f32_16x16x32_f16(kh1, qh[s][1], a, 0, 0, 0);
                a = __builtin_amdgcn_mfma_f32_16x16x32_f16(kl0, qh[s][0], a, 0, 0, 0);
                a = __builtin_amdgcn_mfma_f32_16x16x32_f16(kl1, qh[s][1], a, 0, 0, 0);
                a = __builtin_amdgcn_mfma_f32_16x16x32_f16(kh0, ql[s][0], a, 0, 0, 0);
                a = __builtin_amdgcn_mfma_f32_16x16x32_f16(kh1, ql[s][1], a, 0, 0, 0);
                __builtin_amdgcn_s_setprio(0);
                f16x4 pv;
                #pragma unroll
                for (int r = 0; r < 4; ++r) pv[r] = (_Float16)__sinf(a[r]);
                *(f16x4*)((char*)&Pw[w][0][0] + s * 2048 + lr * 128
                          + (((2*nt + (lq >> 1)) ^ m7) << 4) + ((lq & 1) << 3)) = pv;
            }
        }
        f16x8 ph[2][2];
        #pragma unroll
        for (int s = 0; s < 2; ++s) {
            ph[s][0] = *(const f16x8*)((const char*)&Pw[w][0][0] + s * 2048 + lr * 128 + x0);
            ph[s][1] = *(const f16x8*)((const char*)&Pw[w][0][0] + s * 2048 + lr * 128 + x1);
        }
        #pragma unroll
        for (int nt = 0; nt < 4; ++nt) {
            const int rb = (16*nt + lr) * 128;
            f16x8 kh0 = *(const f16x8*)((const char*)KdH + rb + x0);
            f16x8 kh1 = *(const f16x8*)((const char*)KdH + rb + x1);
            __builtin_amdgcn_s_setprio(1);
            #pragma unroll
            for (int s = 0; s < 2; ++s) {
                Facc[s][nt] = __builtin_amdgcn_mfma_f32_16x16x32_f16(ph[s][0], kh0, Facc[s][nt], 0, 0, 0);
                Facc[s][nt] = __builtin_amdgcn_mfma_f32_16x16x32_f16(ph[s][1], kh1, Facc[s][nt], 0, 0, 0);
            }
            __builtin_amdgcn_s_setprio(0);
        }
        __builtin_amdgcn_s_barrier();
        asm volatile("" ::: "memory");
    }
#undef GLOAD

    #pragma unroll
    for (int s = 0; s < 2; ++s) {
        float* fo = Fout + ((size_t)b * TT + i0 + 16*s + 4*lq) * 256 + h * 64 + lr;
        #pragma unroll
        for (int nt = 0; nt < 4; ++nt)
            #pragma unroll
            for (int r = 0; r < 4; ++r)
                fo[(size_t)r * 256 + nt * 16] = Facc[s][nt][r];
    }
}

extern "C" void kernel_launch(void* const* d_in, const int* in_sizes, int n_in,
                              void* d_out, int out_size, void* d_ws, size_t ws_size,
                              hipStream_t stream) {
    const float* z     = (const float*)d_in[0];
    const float* omega = (const float*)d_in[1];
    const float* Wqk   = (const float*)d_in[2];
    const float* Wout  = (const float*)d_in[3];
    const float* bout  = (const float*)d_in[4];

    float* x    = (float*)d_ws;                  // [BT,256] fp32 state
    float* Facc = x + FSZ;                       // [BT,256] weighted force accumulator
    float* Fp   = Facc + FSZ;                    // [3][BT,256] fp32 partial forces
    float* qkx  = Fp + 3 * FSZ;                  // [BT,512] raw qk of step-start x
    float* qkob = qkx + (size_t)BT * 512;        // [512]
    _Float16* xsH  = (_Float16*)(qkob + 512);    // doubles as reduced-F split buffer
    _Float16* xsL  = xsH  + FSZ;
    _Float16* Qhi  = xsL  + FSZ;
    _Float16* Qlo  = Qhi  + HSZ;
    _Float16* Khi  = Qlo  + HSZ;
    _Float16* Klo  = Khi  + HSZ;
    _Float16* KtrH = Klo  + HSZ;
    _Float16* WqkH = KtrH + HSZ;
    _Float16* WqkL = WqkH + (size_t)512 * 256;
    _Float16* WoutH= WqkL + (size_t)512 * 256;
    _Float16* WoutL= WoutH + (size_t)256 * 256;
    _Float16* WcombH = WoutL + (size_t)256 * 256;   // [512,256]
    _Float16* WcombL = WcombH + (size_t)512 * 256;

    split_weights<<<192, 256, 0, stream>>>(Wqk, Wout, WqkH, WqkL, WoutH, WoutL);
    comb_weights<<<512, 256, 0, stream>>>(Wqk, Wout, omega, bout, WcombH, WcombL, qkob);

    for (int step = 0; step < 4; ++step) {
        l2norm_rows<<<BT / 4, 256, 0, stream>>>(step == 0 ? z : x, x, xsH, xsL);
        // stage 0: qk = x@Wqk^T (stores qkx + emits Q/K)
        gemm_mfma<<<dim3(BT / 128, 8), 256, 0, stream>>>(
            xsH, xsL, WqkH, WqkL, qkx, nullptr,
            nullptr, nullptr, nullptr, nullptr,
            Qhi, Qlo, Khi, Klo, KtrH, 0, 0.f);
        kuramoto_attn<<<dim3(NB * NH, 3, TT / 128), 256, 0, stream>>>(
            Qhi, Qlo, Khi, Klo, KtrH, Fp);
        // stages 1..3: reduce partials once, then qk_s = qkx + c_s*(Fs@Wcomb + qkob)
        for (int s = 1; s <= 3; ++s) {
            const float cs = (s == 3) ? 0.25f : 0.125f;
            reduce_F<<<2048, 256, 0, stream>>>(Fp, Facc, xsH, xsL, (s == 1) ? 1 : 2);
            gemm_mfma<<<dim3(BT / 128, 8), 256, 0, stream>>>(
                xsH, xsL, WcombH, WcombL, qkx, qkob,
                nullptr, nullptr, nullptr, nullptr,
                Qhi, Qlo, Khi, Klo, KtrH, 1, cs);
            kuramoto_attn<<<dim3(NB * NH, 3, TT / 128), 256, 0, stream>>>(
                Qhi, Qlo, Khi, Klo, KtrH, Fp);
        }
        // final: x += DT/6 * (Facc + F4)@Wout^T + DT*(omega+bout)
        reduce_F<<<2048, 256, 0, stream>>>(Fp, Facc, xsH, xsL, 3);
        gemm_mfma<<<dim3(BT / 128, 4), 256, 0, stream>>>(
            xsH, xsL, WoutH, WoutL, nullptr, nullptr,
            omega, bout, x, x,
            nullptr, nullptr, nullptr, nullptr, nullptr, 2, 0.f);
    }
    l2norm_rows<<<BT / 4, 256, 0, stream>>>(x, (float*)d_out, nullptr, nullptr);
}